// Round 1
// baseline (607.487 us; speedup 1.0000x reference)
//
#include <hip/hip_runtime.h>
#include <stdint.h>

typedef unsigned short u16;
typedef unsigned int   u32;
typedef float f32x4 __attribute__((ext_vector_type(4)));
typedef short s16x8 __attribute__((ext_vector_type(8)));

#define T_SEQ 2048
#define NE    2048
#define NH    16
#define NKV   4
#define HD    128

__device__ __forceinline__ u16 f2bf(float f){
  u32 u = __float_as_uint(f);
  u32 r = u + 0x7FFFu + ((u >> 16) & 1u);   // RNE
  return (u16)(r >> 16);
}
__device__ __forceinline__ float bf2f(u16 h){ return __uint_as_float(((u32)h) << 16); }

typedef __attribute__((address_space(3))) u32 lds_u32;
typedef __attribute__((address_space(1))) u32 glb_u32;
__device__ __forceinline__ void g2lds16(const void* g, void* l){
  // async global->LDS, 16B/lane; LDS dest = wave-uniform base + lane*16 (HW)
  __builtin_amdgcn_global_load_lds((const glb_u32*)g, (lds_u32*)l, 16, 0, 0);
}

// ---------------- elementwise fp32 -> bf16 ----------------
__global__ __launch_bounds__(256) void k_cvt(const float* __restrict__ in, u16* __restrict__ out, int n){
  int i = (blockIdx.x * 256 + threadIdx.x) * 4;
  if (i + 3 < n){
    float4 v = *(const float4*)(in + i);
    ushort4 o; o.x = f2bf(v.x); o.y = f2bf(v.y); o.z = f2bf(v.z); o.w = f2bf(v.w);
    *(ushort4*)(out + i) = o;
  }
}

// ---------------- transpose + convert: W[R][C] fp32 -> WT[C][R] bf16 ----------------
__global__ __launch_bounds__(256) void k_tcvt(const float* __restrict__ in, u16* __restrict__ out, int R, int C){
  __shared__ float t[32][33];
  const int r0 = blockIdx.x * 32, c0 = blockIdx.y * 32;
  const int tx = threadIdx.x, ty = threadIdx.y; // (32,8)
  #pragma unroll
  for (int i = 0; i < 4; ++i) t[ty + i*8][tx] = in[(size_t)(r0 + ty + i*8) * C + c0 + tx];
  __syncthreads();
  #pragma unroll
  for (int i = 0; i < 4; ++i) out[(size_t)(c0 + ty + i*8) * R + r0 + tx] = f2bf(t[tx][ty + i*8]);
}

// ---------------- batched bf16 transpose for V: per b, [T][512] -> [512][T] ----------------
__global__ __launch_bounds__(256) void k_tv(const u16* __restrict__ in, u16* __restrict__ out){
  __shared__ u16 t[32][33];
  const int r0 = blockIdx.x * 32, c0 = blockIdx.y * 32, b = blockIdx.z;
  const u16* ib = in  + (size_t)b * T_SEQ * 512;
  u16*       ob = out + (size_t)b * 512 * T_SEQ;
  const int tx = threadIdx.x, ty = threadIdx.y;
  #pragma unroll
  for (int i = 0; i < 4; ++i) t[ty + i*8][tx] = ib[(size_t)(r0 + ty + i*8) * 512 + c0 + tx];
  __syncthreads();
  #pragma unroll
  for (int i = 0; i < 4; ++i) ob[(size_t)(c0 + ty + i*8) * T_SEQ + r0 + tx] = t[tx][ty + i*8];
}

// ---------------- RoPE cos/sin tables [T][64] fp32 ----------------
__global__ __launch_bounds__(256) void k_tab(float* __restrict__ cosT, float* __restrict__ sinT){
  int i = blockIdx.x * 256 + threadIdx.x;  // t*64 + j
  int t = i >> 6, j = i & 63;
  float inv = expf(-(float)j * (11.512925464970229f / 64.0f));  // ln(1e5)
  float f = (float)t * inv;
  cosT[i] = cosf(f);
  sinT[i] = sinf(f);
}

// ---------------- RoPE + RMS-norm, in place on bf16 rows of 128 (1 wave / row) ----------------
__global__ __launch_bounds__(256) void k_rope(u16* __restrict__ qk, const float* __restrict__ cosT,
                                              const float* __restrict__ sinT, int heads){
  const int wid = threadIdx.x >> 6, lane = threadIdx.x & 63;
  const int row = blockIdx.x * 4 + wid;          // row = (b*T + t)*heads + h
  const int t = (row / heads) % T_SEQ;
  u16* p = qk + (size_t)row * HD;
  float x1 = bf2f(p[lane]), x2 = bf2f(p[lane + 64]);
  float c = cosT[t * 64 + lane], s = sinT[t * 64 + lane];
  float y1 = x1 * c + x2 * s;
  float y2 = x2 * c - x1 * s;
  float sq = y1 * y1 + y2 * y2;
  #pragma unroll
  for (int off = 32; off; off >>= 1) sq += __shfl_xor(sq, off);
  float sc = rsqrtf(sq * (1.0f / 128.0f) + 1e-6f);
  p[lane]      = f2bf(y1 * sc);
  p[lane + 64] = f2bf(y2 * sc);
}

// ---------------- GEMM (m97 structure): C[M][N] = A[M][K] * BT[N][K]^T ----------------
__device__ __forceinline__ void cstore(u16* C, size_t i, float v){ C[i] = f2bf(v); }
__device__ __forceinline__ void cstore(float* C, size_t i, float v){ C[i] = v; }

template <typename CT>
__global__ __launch_bounds__(256) void k_gemm(const u16* __restrict__ A, const u16* __restrict__ BT,
                                              CT* __restrict__ C, int M, int N, int K){
  __shared__ u16 As[128 * 32];
  __shared__ u16 Bs[128 * 32];
  const int tid  = threadIdx.x;
  const int lane = tid & 63;
  const int wid  = tid >> 6;
  const int wr = wid >> 1, wc = wid & 1;
  const int tm0 = blockIdx.x * 128, tn0 = blockIdx.y * 128;
  const int rA   = wid * 32 + (lane >> 2);   // staging row for this lane (chunk 0 of 2)
  const int kkst = (lane & 3) * 8;           // staging k offset
  f32x4 acc[4][4] = {};
  const int nkt = K >> 5;
  for (int kt = 0; kt < nkt; ++kt){
    const int k0 = kt * 32;
    const u16* gA = A  + (size_t)(tm0 + rA) * K + k0 + kkst;
    const u16* gB = BT + (size_t)(tn0 + rA) * K + k0 + kkst;
    g2lds16(gA,            &As[wid * 1024]);
    g2lds16(gA + 16 * K,   &As[wid * 1024 + 512]);
    g2lds16(gB,            &Bs[wid * 1024]);
    g2lds16(gB + 16 * K,   &Bs[wid * 1024 + 512]);
    __syncthreads();
    s16x8 af[4], bfr[4];
    #pragma unroll
    for (int m = 0; m < 4; ++m)
      af[m] = *(const s16x8*)&As[(wr * 64 + m * 16 + (lane & 15)) * 32 + (lane >> 4) * 8];
    #pragma unroll
    for (int n = 0; n < 4; ++n)
      bfr[n] = *(const s16x8*)&Bs[(wc * 64 + n * 16 + (lane & 15)) * 32 + (lane >> 4) * 8];
    #pragma unroll
    for (int m = 0; m < 4; ++m)
      #pragma unroll
      for (int n = 0; n < 4; ++n)
        acc[m][n] = __builtin_amdgcn_mfma_f32_16x16x32_bf16(af[m], bfr[n], acc[m][n], 0, 0, 0);
    __syncthreads();
  }
  #pragma unroll
  for (int m = 0; m < 4; ++m){
    const int row0 = tm0 + wr * 64 + m * 16 + ((lane >> 4) << 2);
    #pragma unroll
    for (int n = 0; n < 4; ++n){
      const int col = tn0 + wc * 64 + n * 16 + (lane & 15);
      #pragma unroll
      for (int r = 0; r < 4; ++r)
        cstore(C, (size_t)(row0 + r) * N + col, acc[m][n][r]);
    }
  }
}

// ---------------- flash attention: 1 wave / (b, h, 16 q-rows), KBLK=32 ----------------
__global__ __launch_bounds__(64) void k_attn(const u16* __restrict__ qb, const u16* __restrict__ kb,
                                             const u16* __restrict__ vt, u16* __restrict__ yb){
  __shared__ u16 P[16 * 32];
  const int lane = threadIdx.x;
  const int g = lane >> 4, c = lane & 15;
  const int qb0 = blockIdx.x * 16;
  const int h = blockIdx.y, b = blockIdx.z, kvh = h >> 2;

  // Q fragments (A operand): row = lane&15, k = g*8+j, 4 chunks cover D=128
  const u16* qrow = qb + ((size_t)(b * T_SEQ + qb0 + c) * NE + h * HD + g * 8);
  s16x8 qa[4];
  #pragma unroll
  for (int kc = 0; kc < 4; ++kc) qa[kc] = *(const s16x8*)(qrow + kc * 32);

  f32x4 O[8] = {};
  float m[4], l[4];
  #pragma unroll
  for (int r = 0; r < 4; ++r){ m[r] = -1e30f; l[r] = 0.0f; }

  const u16* kbase = kb + ((size_t)b * T_SEQ * 512 + kvh * HD + g * 8);
  const u16* vbase = vt + ((size_t)(b * 512 + kvh * HD)) * T_SEQ;
  const int nkb = (qb0 + 47) >> 5;           // 32-key blocks covering keys 0..qb0+15
  const float scale = 0.08838834764831845f;  // 1/sqrt(128)

  for (int kblk = 0; kblk < nkb; ++kblk){
    const int ks = kblk * 32;
    f32x4 S0 = {}, S1 = {};
    const u16* k0p = kbase + (size_t)(ks + c) * 512;
    const u16* k1p = k0p + (size_t)16 * 512;
    #pragma unroll
    for (int kc = 0; kc < 4; ++kc){
      s16x8 b0 = *(const s16x8*)(k0p + kc * 32);
      S0 = __builtin_amdgcn_mfma_f32_16x16x32_bf16(qa[kc], b0, S0, 0, 0, 0);
    }
    #pragma unroll
    for (int kc = 0; kc < 4; ++kc){
      s16x8 b1 = *(const s16x8*)(k1p + kc * 32);
      S1 = __builtin_amdgcn_mfma_f32_16x16x32_bf16(qa[kc], b1, S1, 0, 0, 0);
    }
    // online softmax: rows g*4+r spread across the 16 lanes of group g (cols)
    float p0[4], p1[4], al[4];
    const int tq = qb0 + g * 4;
    #pragma unroll
    for (int r = 0; r < 4; ++r){
      float v0 = S0[r] * scale, v1 = S1[r] * scale;
      if (ks + c      > tq + r) v0 = -1e4f;  // causal mask (matches ref MASK_VAL=-1e4)
      if (ks + 16 + c > tq + r) v1 = -1e4f;
      float mr = fmaxf(v0, v1);
      mr = fmaxf(mr, __shfl_xor(mr, 1));
      mr = fmaxf(mr, __shfl_xor(mr, 2));
      mr = fmaxf(mr, __shfl_xor(mr, 4));
      mr = fmaxf(mr, __shfl_xor(mr, 8));
      float mn = fmaxf(m[r], mr);
      float a  = __expf(m[r] - mn);
      m[r] = mn;
      v0 = __expf(v0 - mn); v1 = __expf(v1 - mn);
      float rs = v0 + v1;
      rs += __shfl_xor(rs, 1); rs += __shfl_xor(rs, 2);
      rs += __shfl_xor(rs, 4); rs += __shfl_xor(rs, 8);
      l[r] = l[r] * a + rs;
      al[r] = a;
      p0[r] = v0; p1[r] = v1;
    }
    #pragma unroll
    for (int dt = 0; dt < 8; ++dt)
      #pragma unroll
      for (int r = 0; r < 4; ++r) O[dt][r] *= al[r];
    // P tile (16x32 bf16) through LDS to re-layout acc -> A-fragment
    #pragma unroll
    for (int r = 0; r < 4; ++r){
      P[(g * 4 + r) * 32 + c]      = f2bf(p0[r]);
      P[(g * 4 + r) * 32 + 16 + c] = f2bf(p1[r]);
    }
    __syncthreads();
    s16x8 pa = *(const s16x8*)&P[c * 32 + g * 8];
    const u16* vp = vbase + ks + g * 8;
    #pragma unroll
    for (int dt = 0; dt < 8; ++dt){
      s16x8 vf = *(const s16x8*)(vp + (size_t)(dt * 16 + c) * T_SEQ);
      O[dt] = __builtin_amdgcn_mfma_f32_16x16x32_bf16(pa, vf, O[dt], 0, 0, 0);
    }
    __syncthreads();
  }
  float inv[4];
  #pragma unroll
  for (int r = 0; r < 4; ++r) inv[r] = 1.0f / l[r];
  u16* yrow = yb + ((size_t)(b * T_SEQ + qb0 + g * 4) * NE + h * HD);
  #pragma unroll
  for (int dt = 0; dt < 8; ++dt)
    #pragma unroll
    for (int r = 0; r < 4; ++r)
      yrow[(size_t)r * NE + dt * 16 + c] = f2bf(O[dt][r] * inv[r]);
}

// ---------------- launch ----------------
extern "C" void kernel_launch(void* const* d_in, const int* in_sizes, int n_in,
                              void* d_out, int out_size, void* d_ws, size_t ws_size,
                              hipStream_t stream){
  const float* x  = (const float*)d_in[0];
  const float* wq = (const float*)d_in[1];
  const float* wk = (const float*)d_in[2];
  const float* wv = (const float*)d_in[3];
  const float* wo = (const float*)d_in[4];
  float* out = (float*)d_out;

  char* w = (char*)d_ws;
  u16* xb  = (u16*)w;  w += (size_t)4096 * 2048 * 2;   // 16 MB
  u16* wqT = (u16*)w;  w += (size_t)2048 * 2048 * 2;   //  8 MB
  u16* wkT = (u16*)w;  w += (size_t)512  * 2048 * 2;   //  2 MB
  u16* wvT = (u16*)w;  w += (size_t)512  * 2048 * 2;   //  2 MB
  u16* woT = (u16*)w;  w += (size_t)2048 * 2048 * 2;   //  8 MB
  u16* qb  = (u16*)w;  w += (size_t)4096 * 2048 * 2;   // 16 MB
  u16* kb  = (u16*)w;  w += (size_t)4096 * 512  * 2;   //  4 MB
  u16* vb  = (u16*)w;  w += (size_t)4096 * 512  * 2;   //  4 MB
  u16* vt  = (u16*)w;  w += (size_t)4096 * 512  * 2;   //  4 MB
  u16* yb  = (u16*)w;  w += (size_t)4096 * 2048 * 2;   // 16 MB
  float* cosT = (float*)w; w += (size_t)2048 * 64 * 4; // 0.5 MB
  float* sinT = (float*)w; w += (size_t)2048 * 64 * 4; // 0.5 MB

  // 1) dtype prep
  k_cvt <<<8192, 256, 0, stream>>>(x, xb, 4096 * 2048);
  k_tcvt<<<dim3(64, 64), dim3(32, 8), 0, stream>>>(wq, wqT, 2048, 2048);
  k_tcvt<<<dim3(64, 16), dim3(32, 8), 0, stream>>>(wk, wkT, 2048, 512);
  k_tcvt<<<dim3(64, 16), dim3(32, 8), 0, stream>>>(wv, wvT, 2048, 512);
  k_tcvt<<<dim3(64, 64), dim3(32, 8), 0, stream>>>(wo, woT, 2048, 2048);
  k_tab <<<512, 256, 0, stream>>>(cosT, sinT);

  // 2) projections
  k_gemm<u16><<<dim3(32, 16), 256, 0, stream>>>(xb, wqT, qb, 4096, 2048, 2048);
  k_gemm<u16><<<dim3(32, 4),  256, 0, stream>>>(xb, wkT, kb, 4096, 512,  2048);
  k_gemm<u16><<<dim3(32, 4),  256, 0, stream>>>(xb, wvT, vb, 4096, 512,  2048);

  // 3) RoPE + RMS-norm (in place), V transpose
  k_rope<<<65536 / 4, 256, 0, stream>>>(qb, cosT, sinT, NH);
  k_rope<<<16384 / 4, 256, 0, stream>>>(kb, cosT, sinT, NKV);
  k_tv  <<<dim3(64, 16, 2), dim3(32, 8), 0, stream>>>(vb, vt);

  // 4) causal flash attention
  k_attn<<<dim3(128, 16, 2), 64, 0, stream>>>(qb, kb, vt, yb);

  // 5) output projection -> fp32
  k_gemm<float><<<dim3(32, 16), 256, 0, stream>>>(yb, woT, out, 4096, 2048, 2048);
}

// Round 2
// 329.524 us; speedup vs baseline: 1.8435x; 1.8435x over previous
//
#include <hip/hip_runtime.h>
#include <stdint.h>

typedef unsigned short u16;
typedef unsigned int   u32;
typedef float f32x4 __attribute__((ext_vector_type(4)));
typedef short s16x8 __attribute__((ext_vector_type(8)));

#define T_SEQ 2048
#define NE    2048
#define NH    16
#define NKV   4
#define HD    128

__device__ __forceinline__ u16 f2bf(float f){
  u32 u = __float_as_uint(f);
  u32 r = u + 0x7FFFu + ((u >> 16) & 1u);   // RNE
  return (u16)(r >> 16);
}
__device__ __forceinline__ float bf2f(u16 h){ return __uint_as_float(((u32)h) << 16); }

typedef __attribute__((address_space(3))) u32 lds_u32;
typedef __attribute__((address_space(1))) u32 glb_u32;
__device__ __forceinline__ void g2lds16(const void* g, void* l){
  // async global->LDS, 16B/lane; LDS dest = wave-uniform base + lane*16 (HW)
  __builtin_amdgcn_global_load_lds((const glb_u32*)g, (lds_u32*)l, 16, 0, 0);
}

// ---------------- elementwise fp32 -> bf16 ----------------
__global__ __launch_bounds__(256) void k_cvt(const float* __restrict__ in, u16* __restrict__ out, int n){
  int i = (blockIdx.x * 256 + threadIdx.x) * 4;
  if (i + 3 < n){
    float4 v = *(const float4*)(in + i);
    ushort4 o; o.x = f2bf(v.x); o.y = f2bf(v.y); o.z = f2bf(v.z); o.w = f2bf(v.w);
    *(ushort4*)(out + i) = o;
  }
}

// ---------------- transpose + convert: W[R][C] fp32 -> WT[C][R] bf16 ----------------
__global__ __launch_bounds__(256) void k_tcvt(const float* __restrict__ in, u16* __restrict__ out, int R, int C){
  __shared__ float t[32][33];
  const int r0 = blockIdx.x * 32, c0 = blockIdx.y * 32;
  const int tx = threadIdx.x, ty = threadIdx.y; // (32,8)
  #pragma unroll
  for (int i = 0; i < 4; ++i) t[ty + i*8][tx] = in[(size_t)(r0 + ty + i*8) * C + c0 + tx];
  __syncthreads();
  #pragma unroll
  for (int i = 0; i < 4; ++i) out[(size_t)(c0 + ty + i*8) * R + r0 + tx] = f2bf(t[tx][ty + i*8]);
}

// ---------------- batched bf16 transpose for V: per b, [T][512] -> [512][T] ----------------
__global__ __launch_bounds__(256) void k_tv(const u16* __restrict__ in, u16* __restrict__ out){
  __shared__ u16 t[32][33];
  const int r0 = blockIdx.x * 32, c0 = blockIdx.y * 32, b = blockIdx.z;
  const u16* ib = in  + (size_t)b * T_SEQ * 512;
  u16*       ob = out + (size_t)b * 512 * T_SEQ;
  const int tx = threadIdx.x, ty = threadIdx.y;
  #pragma unroll
  for (int i = 0; i < 4; ++i) t[ty + i*8][tx] = ib[(size_t)(r0 + ty + i*8) * 512 + c0 + tx];
  __syncthreads();
  #pragma unroll
  for (int i = 0; i < 4; ++i) ob[(size_t)(c0 + ty + i*8) * T_SEQ + r0 + tx] = t[tx][ty + i*8];
}

// ---------------- RoPE cos/sin tables [T][64] fp32 ----------------
__global__ __launch_bounds__(256) void k_tab(float* __restrict__ cosT, float* __restrict__ sinT){
  int i = blockIdx.x * 256 + threadIdx.x;  // t*64 + j
  int t = i >> 6, j = i & 63;
  float inv = expf(-(float)j * (11.512925464970229f / 64.0f));  // ln(1e5)
  float f = (float)t * inv;
  cosT[i] = cosf(f);
  sinT[i] = sinf(f);
}

// ---------------- RoPE + RMS-norm, in place on bf16 rows of 128 (1 wave / row) ----------------
__global__ __launch_bounds__(256) void k_rope(u16* __restrict__ qk, const float* __restrict__ cosT,
                                              const float* __restrict__ sinT, int heads){
  const int wid = threadIdx.x >> 6, lane = threadIdx.x & 63;
  const int row = blockIdx.x * 4 + wid;          // row = (b*T + t)*heads + h
  const int t = (row / heads) % T_SEQ;
  u16* p = qk + (size_t)row * HD;
  float x1 = bf2f(p[lane]), x2 = bf2f(p[lane + 64]);
  float c = cosT[t * 64 + lane], s = sinT[t * 64 + lane];
  float y1 = x1 * c + x2 * s;
  float y2 = x2 * c - x1 * s;
  float sq = y1 * y1 + y2 * y2;
  #pragma unroll
  for (int off = 32; off; off >>= 1) sq += __shfl_xor(sq, off);
  float sc = rsqrtf(sq * (1.0f / 128.0f) + 1e-6f);
  p[lane]      = f2bf(y1 * sc);
  p[lane + 64] = f2bf(y2 * sc);
}

// ---------------- GEMM (m97 structure): C[M][N] = A[M][K] * BT[N][K]^T ----------------
__device__ __forceinline__ void cstore(u16* C, size_t i, float v){ C[i] = f2bf(v); }
__device__ __forceinline__ void cstore(float* C, size_t i, float v){ C[i] = v; }

template <typename CT>
__global__ __launch_bounds__(256) void k_gemm(const u16* __restrict__ A, const u16* __restrict__ BT,
                                              CT* __restrict__ C, int M, int N, int K){
  __shared__ u16 As[128 * 32];
  __shared__ u16 Bs[128 * 32];
  const int tid  = threadIdx.x;
  const int lane = tid & 63;
  const int wid  = tid >> 6;
  const int wr = wid >> 1, wc = wid & 1;
  const int tm0 = blockIdx.x * 128, tn0 = blockIdx.y * 128;
  const int rA   = wid * 32 + (lane >> 2);   // staging row for this lane (chunk 0 of 2)
  const int kkst = (lane & 3) * 8;           // staging k offset
  f32x4 acc[4][4] = {};
  const int nkt = K >> 5;
  for (int kt = 0; kt < nkt; ++kt){
    const int k0 = kt * 32;
    const u16* gA = A  + (size_t)(tm0 + rA) * K + k0 + kkst;
    const u16* gB = BT + (size_t)(tn0 + rA) * K + k0 + kkst;
    g2lds16(gA,            &As[wid * 1024]);
    g2lds16(gA + 16 * K,   &As[wid * 1024 + 512]);
    g2lds16(gB,            &Bs[wid * 1024]);
    g2lds16(gB + 16 * K,   &Bs[wid * 1024 + 512]);
    __syncthreads();
    s16x8 af[4], bfr[4];
    #pragma unroll
    for (int m = 0; m < 4; ++m)
      af[m] = *(const s16x8*)&As[(wr * 64 + m * 16 + (lane & 15)) * 32 + (lane >> 4) * 8];
    #pragma unroll
    for (int n = 0; n < 4; ++n)
      bfr[n] = *(const s16x8*)&Bs[(wc * 64 + n * 16 + (lane & 15)) * 32 + (lane >> 4) * 8];
    #pragma unroll
    for (int m = 0; m < 4; ++m)
      #pragma unroll
      for (int n = 0; n < 4; ++n)
        acc[m][n] = __builtin_amdgcn_mfma_f32_16x16x32_bf16(af[m], bfr[n], acc[m][n], 0, 0, 0);
    __syncthreads();
  }
  #pragma unroll
  for (int m = 0; m < 4; ++m){
    const int row0 = tm0 + wr * 64 + m * 16 + ((lane >> 4) << 2);
    #pragma unroll
    for (int n = 0; n < 4; ++n){
      const int col = tn0 + wc * 64 + n * 16 + (lane & 15);
      #pragma unroll
      for (int r = 0; r < 4; ++r)
        cstore(C, (size_t)(row0 + r) * N + col, acc[m][n][r]);
    }
  }
}

// ---------------- swizzled LDS fragment read (byte ^= (row&7)<<4) ----------------
__device__ __forceinline__ s16x8 lds8(const u16* base, int row, int rowB, int inner){
  int a = row * rowB + inner;
  a ^= (row & 7) << 4;
  return *(const s16x8*)((const char*)base + a);
}

// ---------------- flash attention: 8 waves/block, 128 q-rows, KVBLK=64 ----------------
// Block handles q-tiles {15-p, p} sequentially (uniform 36 kblocks/block).
// K tile [64][128] bf16 (256B rows, dbuf), V^T tile [128][64] (128B rows),
// all XOR-swizzled; staged via global_load_lds with pre-swizzled source.
__global__ __launch_bounds__(512) void k_attn(const u16* __restrict__ qb, const u16* __restrict__ kb,
                                              const u16* __restrict__ vt, u16* __restrict__ yb){
  __shared__ u16 Kt[2][64 * 128];   // 2 x 16 KB
  __shared__ u16 Vt[128 * 64];      // 16 KB
  __shared__ u16 Pt[8][16 * 64];    // 16 KB
  const int tid = threadIdx.x, lane = tid & 63, w = tid >> 6;
  const int g = lane >> 4, c = lane & 15;

  // bijective XCD swizzle: all 32 blocks sharing (b,kvh) land on one XCD
  const int bx = blockIdx.x;
  const int xcd = bx & 7, slot = bx >> 3;
  const int linear = xcd * 32 + slot;          // 0..255
  const int p   = linear & 7;                  // pair index
  const int hl  = (linear >> 3) & 3;
  const int kvh = (linear >> 5) & 3;
  const int b   = (linear >> 7) & 1;
  const int h   = kvh * 4 + hl;

  const u16* kgb = kb + (size_t)(b * T_SEQ) * 512 + kvh * 128;
  const u16* vgb = vt + ((size_t)(b * 512 + kvh * 128)) * T_SEQ;
  u16* Pw = Pt[w];
  const float scale = 0.08838834764831845f;    // 1/sqrt(128)

  for (int ph = 0; ph < 2; ++ph){
    const int tile = (ph == 0) ? (15 - p) : p;
    const int qb0  = tile * 128;
    const int tq0  = qb0 + w * 16;             // this wave's 16 q-rows
    const int nkb  = 2 * tile + 2;

    // Q fragments for this wave's 16 rows
    const u16* qrow = qb + ((size_t)(b * T_SEQ + tq0 + c)) * NE + h * HD + g * 8;
    s16x8 qa[4];
    #pragma unroll
    for (int kc = 0; kc < 4; ++kc) qa[kc] = *(const s16x8*)(qrow + kc * 32);

    f32x4 O[8] = {};
    float m[4], l[4];
    #pragma unroll
    for (int r = 0; r < 4; ++r){ m[r] = -1e30f; l[r] = 0.0f; }

    // ---- staging helpers (each wave does 2 calls of 16; source pre-swizzled) ----
    auto stageK = [&](int kbI, u16* dst){
      const int ks = kbI * 64;
      #pragma unroll
      for (int cc = 0; cc < 2; ++cc){
        const int call = w * 2 + cc;           // 0..15
        const int o = call * 64 + lane;        // LDS 16B-chunk index (16 chunks/row)
        const int f = o ^ ((o >> 4) & 7);      // pre-swizzled logical chunk
        const u16* gp = kgb + (size_t)(ks + (o >> 4)) * 512 + (f & 15) * 8;
        g2lds16(gp, dst + call * 512);
      }
    };
    auto stageV = [&](int kbI){
      const int ks = kbI * 64;
      #pragma unroll
      for (int cc = 0; cc < 2; ++cc){
        const int call = w * 2 + cc;
        const int o = call * 64 + lane;        // 8 chunks/row, row = d
        const int f = o ^ ((o >> 3) & 7);
        const u16* gp = vgb + (size_t)(o >> 3) * T_SEQ + ks + (f & 7) * 8;
        g2lds16(gp, Vt + call * 512);
      }
    };

    // prologue: stage K(0)
    stageK(0, Kt[0]);
    asm volatile("s_waitcnt vmcnt(0)" ::: "memory");
    __syncthreads();
    int cur = 0;

    for (int kbI = 0; kbI < nkb; ++kbI){
      const int ks = kbI * 64;
      stageV(kbI);
      if (kbI + 1 < nkb) stageK(kbI + 1, Kt[cur ^ 1]);

      const bool active = (ks <= tq0 + 15);
      s16x8 pa0, pa1;
      if (active){
        // QK^T: S[n] covers keys ks + n*16 + c
        f32x4 S[4] = {};
        const u16* Kc = Kt[cur];
        #pragma unroll
        for (int n = 0; n < 4; ++n)
          #pragma unroll
          for (int kc = 0; kc < 4; ++kc)
            S[n] = __builtin_amdgcn_mfma_f32_16x16x32_bf16(qa[kc], lds8(Kc, n * 16 + c, 256, kc * 64 + g * 16), S[n], 0, 0, 0);

        // online softmax, rows tq0 + g*4 + r
        float al[4];
        #pragma unroll
        for (int r = 0; r < 4; ++r){
          const int tq = tq0 + g * 4 + r;
          float vv[4];
          #pragma unroll
          for (int n = 0; n < 4; ++n){
            float x = S[n][r] * scale;
            vv[n] = (ks + n * 16 + c > tq) ? -1e4f : x;
          }
          float mr = fmaxf(fmaxf(vv[0], vv[1]), fmaxf(vv[2], vv[3]));
          mr = fmaxf(mr, __shfl_xor(mr, 1));
          mr = fmaxf(mr, __shfl_xor(mr, 2));
          mr = fmaxf(mr, __shfl_xor(mr, 4));
          mr = fmaxf(mr, __shfl_xor(mr, 8));
          float mn = fmaxf(m[r], mr);
          float a  = __expf(m[r] - mn);
          float rs = 0.0f;
          #pragma unroll
          for (int n = 0; n < 4; ++n){ vv[n] = __expf(vv[n] - mn); rs += vv[n]; }
          rs += __shfl_xor(rs, 1); rs += __shfl_xor(rs, 2);
          rs += __shfl_xor(rs, 4); rs += __shfl_xor(rs, 8);
          m[r] = mn; l[r] = l[r] * a + rs; al[r] = a;
          // write P row (swizzled)
          #pragma unroll
          for (int n = 0; n < 4; ++n){
            int aB = (g * 4 + r) * 128 + (n * 16 + c) * 2;
            aB ^= ((g * 4 + r) & 7) << 4;
            *(u16*)((char*)Pw + aB) = f2bf(vv[n]);
          }
        }
        #pragma unroll
        for (int dt = 0; dt < 8; ++dt)
          #pragma unroll
          for (int r = 0; r < 4; ++r) O[dt][r] *= al[r];
        // P fragments (A-operand): row c, k = kk*32 + g*8 + j
        pa0 = lds8(Pw, c, 128, g * 16);
        pa1 = lds8(Pw, c, 128, 64 + g * 16);
      }

      asm volatile("s_waitcnt vmcnt(0)" ::: "memory");
      __syncthreads();   // V(kbI) + K(kbI+1) staged, visible to all

      if (active){
        #pragma unroll
        for (int dt = 0; dt < 8; ++dt){
          O[dt] = __builtin_amdgcn_mfma_f32_16x16x32_bf16(pa0, lds8(Vt, dt * 16 + c, 128, g * 16), O[dt], 0, 0, 0);
          O[dt] = __builtin_amdgcn_mfma_f32_16x16x32_bf16(pa1, lds8(Vt, dt * 16 + c, 128, 64 + g * 16), O[dt], 0, 0, 0);
        }
      }
      __syncthreads();   // PV done before next V/K staging overwrites
      cur ^= 1;
    }

    // epilogue: normalize + store this phase's 16 rows
    float inv[4];
    #pragma unroll
    for (int r = 0; r < 4; ++r) inv[r] = 1.0f / l[r];
    u16* yrow = yb + ((size_t)(b * T_SEQ + tq0 + g * 4)) * NE + h * HD;
    #pragma unroll
    for (int dt = 0; dt < 8; ++dt)
      #pragma unroll
      for (int r = 0; r < 4; ++r)
        yrow[(size_t)r * NE + dt * 16 + c] = f2bf(O[dt][r] * inv[r]);
  }
}

// ---------------- launch ----------------
extern "C" void kernel_launch(void* const* d_in, const int* in_sizes, int n_in,
                              void* d_out, int out_size, void* d_ws, size_t ws_size,
                              hipStream_t stream){
  const float* x  = (const float*)d_in[0];
  const float* wq = (const float*)d_in[1];
  const float* wk = (const float*)d_in[2];
  const float* wv = (const float*)d_in[3];
  const float* wo = (const float*)d_in[4];
  float* out = (float*)d_out;

  char* w = (char*)d_ws;
  u16* xb  = (u16*)w;  w += (size_t)4096 * 2048 * 2;   // 16 MB
  u16* wqT = (u16*)w;  w += (size_t)2048 * 2048 * 2;   //  8 MB
  u16* wkT = (u16*)w;  w += (size_t)512  * 2048 * 2;   //  2 MB
  u16* wvT = (u16*)w;  w += (size_t)512  * 2048 * 2;   //  2 MB
  u16* woT = (u16*)w;  w += (size_t)2048 * 2048 * 2;   //  8 MB
  u16* qb  = (u16*)w;  w += (size_t)4096 * 2048 * 2;   // 16 MB
  u16* kb  = (u16*)w;  w += (size_t)4096 * 512  * 2;   //  4 MB
  u16* vb  = (u16*)w;  w += (size_t)4096 * 512  * 2;   //  4 MB
  u16* vt  = (u16*)w;  w += (size_t)4096 * 512  * 2;   //  4 MB
  u16* yb  = (u16*)w;  w += (size_t)4096 * 2048 * 2;   // 16 MB
  float* cosT = (float*)w; w += (size_t)2048 * 64 * 4; // 0.5 MB
  float* sinT = (float*)w; w += (size_t)2048 * 64 * 4; // 0.5 MB

  // 1) dtype prep
  k_cvt <<<8192, 256, 0, stream>>>(x, xb, 4096 * 2048);
  k_tcvt<<<dim3(64, 64), dim3(32, 8), 0, stream>>>(wq, wqT, 2048, 2048);
  k_tcvt<<<dim3(64, 16), dim3(32, 8), 0, stream>>>(wk, wkT, 2048, 512);
  k_tcvt<<<dim3(64, 16), dim3(32, 8), 0, stream>>>(wv, wvT, 2048, 512);
  k_tcvt<<<dim3(64, 64), dim3(32, 8), 0, stream>>>(wo, woT, 2048, 2048);
  k_tab <<<512, 256, 0, stream>>>(cosT, sinT);

  // 2) projections
  k_gemm<u16><<<dim3(32, 16), 256, 0, stream>>>(xb, wqT, qb, 4096, 2048, 2048);
  k_gemm<u16><<<dim3(32, 4),  256, 0, stream>>>(xb, wkT, kb, 4096, 512,  2048);
  k_gemm<u16><<<dim3(32, 4),  256, 0, stream>>>(xb, wvT, vb, 4096, 512,  2048);

  // 3) RoPE + RMS-norm (in place), V transpose
  k_rope<<<65536 / 4, 256, 0, stream>>>(qb, cosT, sinT, NH);
  k_rope<<<16384 / 4, 256, 0, stream>>>(kb, cosT, sinT, NKV);
  k_tv  <<<dim3(64, 16, 2), dim3(32, 8), 0, stream>>>(vb, vt);

  // 4) causal flash attention (8-wave blocks, paired tiles, XCD-grouped)
  k_attn<<<256, 512, 0, stream>>>(qb, kb, vt, yb);

  // 5) output projection -> fp32
  k_gemm<float><<<dim3(32, 16), 256, 0, stream>>>(yb, woT, out, 4096, 2048, 2048);
}

// Round 3
// 243.504 us; speedup vs baseline: 2.4948x; 1.3533x over previous
//
#include <hip/hip_runtime.h>
#include <stdint.h>

typedef unsigned short u16;
typedef unsigned int   u32;
typedef float f32x4  __attribute__((ext_vector_type(4)));
typedef float f32x16 __attribute__((ext_vector_type(16)));
typedef short s16x8  __attribute__((ext_vector_type(8)));

#define T_SEQ 2048
#define NE    2048
#define NH    16
#define NKV   4
#define HD    128
#define QKVW  3072   // fused qkv row width

__device__ __forceinline__ u16 f2bf(float f){
  u32 u = __float_as_uint(f);
  u32 r = u + 0x7FFFu + ((u >> 16) & 1u);   // RNE
  return (u16)(r >> 16);
}
__device__ __forceinline__ float bf2f(u16 h){ return __uint_as_float(((u32)h) << 16); }

// packed f32x2 -> bf16x2 (RNE), no builtin on gfx950
__device__ __forceinline__ u32 pkbf(float a, float b){
  u32 r; asm("v_cvt_pk_bf16_f32 %0, %1, %2" : "=v"(r) : "v"(a), "v"(b)); return r;
}

typedef __attribute__((address_space(3))) u32 lds_u32;
typedef __attribute__((address_space(1))) u32 glb_u32;
__device__ __forceinline__ void g2lds16(const void* g, void* l){
  __builtin_amdgcn_global_load_lds((const glb_u32*)g, (lds_u32*)l, 16, 0, 0);
}

// ---------------- elementwise fp32 -> bf16 ----------------
__global__ __launch_bounds__(256) void k_cvt(const float* __restrict__ in, u16* __restrict__ out, int n){
  int i = (blockIdx.x * 256 + threadIdx.x) * 4;
  if (i + 3 < n){
    float4 v = *(const float4*)(in + i);
    ushort4 o; o.x = f2bf(v.x); o.y = f2bf(v.y); o.z = f2bf(v.z); o.w = f2bf(v.w);
    *(ushort4*)(out + i) = o;
  }
}

// ---------------- transpose + convert: W[R][C] fp32 -> WT[C][R] bf16 ----------------
__global__ __launch_bounds__(256) void k_tcvt(const float* __restrict__ in, u16* __restrict__ out, int R, int C){
  __shared__ float t[32][33];
  const int r0 = blockIdx.x * 32, c0 = blockIdx.y * 32;
  const int tx = threadIdx.x, ty = threadIdx.y; // (32,8)
  #pragma unroll
  for (int i = 0; i < 4; ++i) t[ty + i*8][tx] = in[(size_t)(r0 + ty + i*8) * C + c0 + tx];
  __syncthreads();
  #pragma unroll
  for (int i = 0; i < 4; ++i) out[(size_t)(c0 + ty + i*8) * R + r0 + tx] = f2bf(t[tx][ty + i*8]);
}

// ---------------- V transpose from fused qkv: per b, [T][512] (cols 2560+) -> [512][T] ----------------
__global__ __launch_bounds__(256) void k_tv(const u16* __restrict__ qkv, u16* __restrict__ out){
  __shared__ u16 t[32][33];
  const int r0 = blockIdx.x * 32, c0 = blockIdx.y * 32, b = blockIdx.z;
  const u16* ib = qkv + (size_t)b * T_SEQ * QKVW + 2560;
  u16*       ob = out + (size_t)b * 512 * T_SEQ;
  const int tx = threadIdx.x, ty = threadIdx.y;
  #pragma unroll
  for (int i = 0; i < 4; ++i) t[ty + i*8][tx] = ib[(size_t)(r0 + ty + i*8) * QKVW + c0 + tx];
  __syncthreads();
  #pragma unroll
  for (int i = 0; i < 4; ++i) ob[(size_t)(c0 + ty + i*8) * T_SEQ + r0 + tx] = t[tx][ty + i*8];
}

// ---------------- RoPE cos/sin tables [T][64] fp32 ----------------
__global__ __launch_bounds__(256) void k_tab(float* __restrict__ cosT, float* __restrict__ sinT){
  int i = blockIdx.x * 256 + threadIdx.x;  // t*64 + j
  int t = i >> 6, j = i & 63;
  float inv = expf(-(float)j * (11.512925464970229f / 64.0f));  // ln(1e5)
  float f = (float)t * inv;
  cosT[i] = cosf(f);
  sinT[i] = sinf(f);
}

// ---------------- RoPE + RMS-norm in place on fused qkv rows (1 wave / head-row) ----------------
__global__ __launch_bounds__(256) void k_rope(u16* __restrict__ base, const float* __restrict__ cosT,
                                              const float* __restrict__ sinT, int log2h, float scale){
  const int wid = threadIdx.x >> 6, lane = threadIdx.x & 63;
  const int rh  = blockIdx.x * 4 + wid;          // row-head index
  const int row = rh >> log2h;                   // b*T + t
  const int h   = rh & ((1 << log2h) - 1);
  const int t   = row & (T_SEQ - 1);
  u16* p = base + (size_t)row * QKVW + h * HD;
  float x1 = bf2f(p[lane]), x2 = bf2f(p[lane + 64]);
  float c = cosT[t * 64 + lane], s = sinT[t * 64 + lane];
  float y1 = x1 * c + x2 * s;
  float y2 = x2 * c - x1 * s;
  float sq = y1 * y1 + y2 * y2;
  #pragma unroll
  for (int off = 32; off; off >>= 1) sq += __shfl_xor(sq, off);
  float sc = rsqrtf(sq * (1.0f / 128.0f) + 1e-6f) * scale;
  p[lane]      = f2bf(y1 * sc);
  p[lane + 64] = f2bf(y2 * sc);
}

// ---------------- GEMM (m97 structure): C[M][N] = A[M][K] * BT[N][K]^T ----------------
__device__ __forceinline__ void cstore(u16* C, size_t i, float v){ C[i] = f2bf(v); }
__device__ __forceinline__ void cstore(float* C, size_t i, float v){ C[i] = v; }

template <typename CT>
__global__ __launch_bounds__(256) void k_gemm(const u16* __restrict__ A, const u16* __restrict__ BT,
                                              CT* __restrict__ C, int M, int N, int K){
  __shared__ u16 As[128 * 32];
  __shared__ u16 Bs[128 * 32];
  const int tid  = threadIdx.x;
  const int lane = tid & 63;
  const int wid  = tid >> 6;
  const int wr = wid >> 1, wc = wid & 1;
  const int tm0 = blockIdx.x * 128, tn0 = blockIdx.y * 128;
  const int rA   = wid * 32 + (lane >> 2);
  const int kkst = (lane & 3) * 8;
  f32x4 acc[4][4] = {};
  const int nkt = K >> 5;
  for (int kt = 0; kt < nkt; ++kt){
    const int k0 = kt * 32;
    const u16* gA = A  + (size_t)(tm0 + rA) * K + k0 + kkst;
    const u16* gB = BT + (size_t)(tn0 + rA) * K + k0 + kkst;
    g2lds16(gA,            &As[wid * 1024]);
    g2lds16(gA + 16 * K,   &As[wid * 1024 + 512]);
    g2lds16(gB,            &Bs[wid * 1024]);
    g2lds16(gB + 16 * K,   &Bs[wid * 1024 + 512]);
    __syncthreads();
    s16x8 af[4], bfr[4];
    #pragma unroll
    for (int m = 0; m < 4; ++m)
      af[m] = *(const s16x8*)&As[(wr * 64 + m * 16 + (lane & 15)) * 32 + (lane >> 4) * 8];
    #pragma unroll
    for (int n = 0; n < 4; ++n)
      bfr[n] = *(const s16x8*)&Bs[(wc * 64 + n * 16 + (lane & 15)) * 32 + (lane >> 4) * 8];
    #pragma unroll
    for (int m = 0; m < 4; ++m)
      #pragma unroll
      for (int n = 0; n < 4; ++n)
        acc[m][n] = __builtin_amdgcn_mfma_f32_16x16x32_bf16(af[m], bfr[n], acc[m][n], 0, 0, 0);
    __syncthreads();
  }
  #pragma unroll
  for (int m = 0; m < 4; ++m){
    const int row0 = tm0 + wr * 64 + m * 16 + ((lane >> 4) << 2);
    #pragma unroll
    for (int n = 0; n < 4; ++n){
      const int col = tn0 + wc * 64 + n * 16 + (lane & 15);
      #pragma unroll
      for (int r = 0; r < 4; ++r)
        cstore(C, (size_t)(row0 + r) * N + col, acc[m][n][r]);
    }
  }
}

// ---------------- swizzled LDS fragment reads (byte ^= (row&7)<<4) ----------------
__device__ __forceinline__ s16x8 ldsK(const u16* base, int row, int colB){
  int a = row * 256 + colB; a ^= (row & 7) << 4;
  return *(const s16x8*)((const char*)base + a);
}
__device__ __forceinline__ s16x8 ldsV(const u16* base, int row, int colB){
  int a = row * 128 + colB; a ^= (row & 7) << 4;
  return *(const s16x8*)((const char*)base + a);
}

// ---------------- flash attention: 8 waves, 32 q-rows/wave, 32x32 MFMA, swapped operands ----------------
// S^T = mfma(K, Q): lane owns one q-row (col = lane&31), keys split across lane halves.
// Softmax fully in-register (lane-local m/l, one shfl_xor(32) cross-half combine).
// P^T -> PV B-operand via cvt_pk_bf16 + shfl_xor(32)/cndmask (no P LDS round trip).
// O^T accumulates per-lane column; defer-max rescale (THR=8).
// Block = (b, h, p): waves 0-3 tile 15-p, waves 4-7 tile p; shared K/V staging (same kvh);
// per-block LDS-read work constant -> balanced. 256 blocks, XCD-grouped by (b,kvh).
__global__ __launch_bounds__(512, 2) void k_attn(const u16* __restrict__ qkv, const u16* __restrict__ vt,
                                                 u16* __restrict__ yb){
  __shared__ u16 Kt[2][64 * 128];   // [key][d], 2 x 16 KB, XOR-swizzled
  __shared__ u16 Vt[128 * 64];      // V^T [d][key], 16 KB, XOR-swizzled
  const int tid = threadIdx.x, lane = tid & 63, w = tid >> 6;
  const int ql = lane & 31, hi = lane >> 5;

  const int bx = blockIdx.x;
  const int linear = (bx & 7) * 32 + (bx >> 3);   // XCD-grouped: 32 blocks/XCD share (b,kvh)
  const int p   = linear & 7;
  const int hl  = (linear >> 3) & 3;
  const int kvh = (linear >> 5) & 3;
  const int b   = (linear >> 7) & 1;
  const int h   = kvh * 4 + hl;

  const int tile = (w < 4) ? (15 - p) : p;
  const int tq0  = tile * 128 + (w & 3) * 32;
  const int myq  = tq0 + ql;
  const int nkb  = 2 * (15 - p) + 2;

  const u16* kg  = qkv + (size_t)(b * T_SEQ) * QKVW + 2048 + kvh * 128;
  const u16* vgb = vt + ((size_t)(b * 512 + kvh * 128)) * T_SEQ;

  auto stageK = [&](int kbI, u16* dst){
    const int ks = kbI * 64;
    #pragma unroll
    for (int cc = 0; cc < 2; ++cc){
      const int call = w * 2 + cc;
      const int o = call * 64 + lane;          // 16B-chunk idx, 16 chunks/row
      const int f = o ^ ((o >> 4) & 7);        // pre-swizzled source chunk
      g2lds16(kg + (size_t)(ks + (o >> 4)) * QKVW + (f & 15) * 8, dst + call * 512);
    }
  };
  auto stageV = [&](int kbI){
    const int ks = kbI * 64;
    #pragma unroll
    for (int cc = 0; cc < 2; ++cc){
      const int call = w * 2 + cc;
      const int o = call * 64 + lane;          // 8 chunks/row, row = d
      const int f = o ^ ((o >> 3) & 7);
      g2lds16(vgb + (size_t)(o >> 3) * T_SEQ + ks + (f & 7) * 8, Vt + call * 512);
    }
  };

  stageK(0, Kt[0]);

  // Q fragments (B operand): col = ql, k(d) = kc*16 + hi*8 + j
  const u16* qrow = qkv + ((size_t)(b * T_SEQ + myq)) * QKVW + h * HD + hi * 8;
  s16x8 qf[8];
  #pragma unroll
  for (int kc = 0; kc < 8; ++kc) qf[kc] = *(const s16x8*)(qrow + kc * 16);

  f32x16 O[4] = {};
  float mloc = -1e30f, lloc = 0.0f;

  asm volatile("s_waitcnt vmcnt(0)" ::: "memory");
  __syncthreads();
  int cur = 0;

  for (int kbI = 0; kbI < nkb; ++kbI){
    const int ks = kbI * 64;
    stageV(kbI);
    if (kbI + 1 < nkb) stageK(kbI + 1, Kt[cur ^ 1]);

    int nkc = 0;
    u32 bw[16];
    if (ks <= tq0 + 31){
      const u16* Kc = Kt[cur];
      const bool doN1 = (ks + 32 <= tq0 + 31);
      f32x16 S0 = {}, S1 = {};
      #pragma unroll
      for (int kc = 0; kc < 8; ++kc)
        S0 = __builtin_amdgcn_mfma_f32_32x32x16_bf16(ldsK(Kc, ql, kc*32 + hi*16), qf[kc], S0, 0, 0, 0);
      if (doN1){
        #pragma unroll
        for (int kc = 0; kc < 8; ++kc)
          S1 = __builtin_amdgcn_mfma_f32_32x32x16_bf16(ldsK(Kc, 32 + ql, kc*32 + hi*16), qf[kc], S1, 0, 0, 0);
      }
      // causal mask; key(r) = ks + ntile*32 + (r&3) + 8*(r>>2) + 4*hi
      if (ks + 31 > tq0){
        #pragma unroll
        for (int r = 0; r < 16; ++r)
          if (ks + (r&3) + 8*(r>>2) + 4*hi > myq) S0[r] = -1e30f;
      }
      if (doN1 && (ks + 63 > tq0)){
        #pragma unroll
        for (int r = 0; r < 16; ++r)
          if (ks + 32 + (r&3) + 8*(r>>2) + 4*hi > myq) S1[r] = -1e30f;
      }
      float mr = -1e30f;
      #pragma unroll
      for (int r = 0; r < 16; ++r) mr = fmaxf(mr, S0[r]);
      if (doN1){
        #pragma unroll
        for (int r = 0; r < 16; ++r) mr = fmaxf(mr, S1[r]);
      }
      mr = fmaxf(mr, __shfl_xor(mr, 32));
      if (!__all(mr <= mloc + 8.0f)){       // defer-max (T13)
        const float mn = fmaxf(mloc, mr);
        const float a  = __expf(mloc - mn);
        mloc = mn; lloc *= a;
        #pragma unroll
        for (int dt = 0; dt < 4; ++dt)
          #pragma unroll
          for (int r = 0; r < 16; ++r) O[dt][r] *= a;
      }
      float rs = 0.0f;
      #pragma unroll
      for (int r = 0; r < 16; ++r){ S0[r] = __expf(S0[r] - mloc); rs += S0[r]; }
      if (doN1){
        #pragma unroll
        for (int r = 0; r < 16; ++r){ S1[r] = __expf(S1[r] - mloc); rs += S1[r]; }
      }
      rs += __shfl_xor(rs, 32);
      lloc += rs;
      // pack P^T -> PV B-frags: word j' of kc covers keys kc*16 + hi*8 + {2j',2j'+1}
      {
        u32 pk[8], pp[8];
        #pragma unroll
        for (int j = 0; j < 8; ++j) pk[j] = pkbf(S0[2*j], S0[2*j+1]);
        #pragma unroll
        for (int j = 0; j < 8; ++j) pp[j] = (u32)__shfl_xor((int)pk[j], 32);
        bw[0] = hi ? pp[2] : pk[0];  bw[1] = hi ? pp[3] : pk[1];
        bw[2] = hi ? pk[2] : pp[0];  bw[3] = hi ? pk[3] : pp[1];
        bw[4] = hi ? pp[6] : pk[4];  bw[5] = hi ? pp[7] : pk[5];
        bw[6] = hi ? pk[6] : pp[4];  bw[7] = hi ? pk[7] : pp[5];
      }
      nkc = 2;
      if (doN1){
        u32 pk[8], pp[8];
        #pragma unroll
        for (int j = 0; j < 8; ++j) pk[j] = pkbf(S1[2*j], S1[2*j+1]);
        #pragma unroll
        for (int j = 0; j < 8; ++j) pp[j] = (u32)__shfl_xor((int)pk[j], 32);
        bw[8]  = hi ? pp[2] : pk[0];  bw[9]  = hi ? pp[3] : pk[1];
        bw[10] = hi ? pk[2] : pp[0];  bw[11] = hi ? pk[3] : pp[1];
        bw[12] = hi ? pp[6] : pk[4];  bw[13] = hi ? pp[7] : pk[5];
        bw[14] = hi ? pk[6] : pp[4];  bw[15] = hi ? pk[7] : pp[5];
        nkc = 4;
      }
    }

    asm volatile("s_waitcnt vmcnt(0)" ::: "memory");
    __syncthreads();   // V(kbI) + K(kbI+1) staged & visible

    #pragma unroll
    for (int kc = 0; kc < 4; ++kc){
      if (kc < nkc){
        union { u32 u[4]; s16x8 v; } pb;
        pb.u[0] = bw[kc*4+0]; pb.u[1] = bw[kc*4+1]; pb.u[2] = bw[kc*4+2]; pb.u[3] = bw[kc*4+3];
        #pragma unroll
        for (int dt = 0; dt < 4; ++dt)
          O[dt] = __builtin_amdgcn_mfma_f32_32x32x16_bf16(ldsV(Vt, dt*32 + ql, kc*32 + hi*16), pb.v, O[dt], 0, 0, 0);
      }
    }
    __syncthreads();   // protect Vt / Kt before next staging
    cur ^= 1;
  }

  // epilogue: normalize, pack, store (lane owns one q-row; d = dt*32 + 8*mq + 4*hi + 0..3)
  const float linv = 1.0f / lloc;
  u16* yr = yb + ((size_t)(b * T_SEQ + myq)) * NE + h * HD;
  #pragma unroll
  for (int dt = 0; dt < 4; ++dt){
    #pragma unroll
    for (int mq = 0; mq < 4; ++mq){
      uint2 s;
      s.x = pkbf(O[dt][4*mq+0] * linv, O[dt][4*mq+1] * linv);
      s.y = pkbf(O[dt][4*mq+2] * linv, O[dt][4*mq+3] * linv);
      *(uint2*)(yr + dt*32 + 8*mq + 4*hi) = s;
    }
  }
}

// ---------------- launch ----------------
extern "C" void kernel_launch(void* const* d_in, const int* in_sizes, int n_in,
                              void* d_out, int out_size, void* d_ws, size_t ws_size,
                              hipStream_t stream){
  const float* x  = (const float*)d_in[0];
  const float* wq = (const float*)d_in[1];
  const float* wk = (const float*)d_in[2];
  const float* wv = (const float*)d_in[3];
  const float* wo = (const float*)d_in[4];
  float* out = (float*)d_out;

  char* w = (char*)d_ws;
  u16* xb    = (u16*)w;  w += (size_t)4096 * 2048 * 2;   // 16 MB
  u16* wqkvT = (u16*)w;  w += (size_t)3072 * 2048 * 2;   // 12 MB  (rows: q 0..2047, k 2048..2559, v 2560..3071)
  u16* woT   = (u16*)w;  w += (size_t)2048 * 2048 * 2;   //  8 MB
  u16* qkv   = (u16*)w;  w += (size_t)4096 * 3072 * 2;   // 24 MB
  u16* vtb   = (u16*)w;  w += (size_t)4096 * 512  * 2;   //  4 MB
  u16* yb    = (u16*)w;  w += (size_t)4096 * 2048 * 2;   // 16 MB
  float* cosT = (float*)w; w += (size_t)2048 * 64 * 4;   // 0.5 MB
  float* sinT = (float*)w; w += (size_t)2048 * 64 * 4;   // 0.5 MB

  const float SCALE = 0.08838834764831845f;  // 1/sqrt(128), folded into q

  // 1) dtype prep (weights fused into one [3072][2048] B^T)
  k_cvt <<<8192, 256, 0, stream>>>(x, xb, 4096 * 2048);
  k_tcvt<<<dim3(64, 64), dim3(32, 8), 0, stream>>>(wq, wqkvT,                     2048, 2048);
  k_tcvt<<<dim3(64, 16), dim3(32, 8), 0, stream>>>(wk, wqkvT + (size_t)2048*2048, 2048, 512);
  k_tcvt<<<dim3(64, 16), dim3(32, 8), 0, stream>>>(wv, wqkvT + (size_t)2560*2048, 2048, 512);
  k_tcvt<<<dim3(64, 64), dim3(32, 8), 0, stream>>>(wo, woT, 2048, 2048);
  k_tab <<<512, 256, 0, stream>>>(cosT, sinT);

  // 2) fused QKV projection: [4096][3072]
  k_gemm<u16><<<dim3(32, 24), 256, 0, stream>>>(xb, wqkvT, qkv, 4096, QKVW, 2048);

  // 3) RoPE + RMS-norm in place (scale folded into q), V transpose
  k_rope<<<16384, 256, 0, stream>>>(qkv,        cosT, sinT, 4, SCALE);  // q: 16 heads
  k_rope<<<4096,  256, 0, stream>>>(qkv + 2048, cosT, sinT, 2, 1.0f);   // k: 4 heads
  k_tv  <<<dim3(64, 16, 2), dim3(32, 8), 0, stream>>>(qkv, vtb);

  // 4) causal flash attention (32x32 MFMA, in-register softmax)
  k_attn<<<256, 512, 0, stream>>>(qkv, vtb, yb);

  // 5) output projection -> fp32
  k_gemm<float><<<dim3(32, 16), 256, 0, stream>>>(yb, woT, out, 4096, 2048, 2048);
}